// Round 2
// baseline (2428.029 us; speedup 1.0000x reference)
//
#include <hip/hip_runtime.h>

#define D 128
#define BROWS 32
#define BSHIFT 5
#define COLBITS 17
#define COLMASK 0x1FFFF
#define CHUNKS 256
#define CAP 1280
#define CVTB 1792
#define PBLK 1024
#define DSPLIT 8      // embedding-dim split: 8 planes of 16 dims (3.3 MB each -> L2-resident per XCD)
#define DIMW 8        // u32 words (2 bf16 dims each) per plane per node
#define ASTRIDE 17    // padded LDS acc stride (floats): 17*row+2*dw spreads banks (~2-way, free)
// XCD-grouping permutation of chunk->matrix-slot (valid for CHUNKS==256):
// consecutive slots (same cache line) belong to chunks with equal c%8 (same XCD).
#define PERM(c) ((((c) & 7) << 5) | ((c) >> 3))

// ---------- Phase 1 (fused): per-chunk bucket histogram + emb fp32->bf16x2 ----------
// bf16 table is written PLANE-MAJOR: q[plane][node][8 words], plane = dim/16.
// Each 3.3 MB plane is gathered only by blocks with blockIdx%8 == plane -> one XCD's L2.
__global__ void k_prep(const int* __restrict__ rows, int E, int CE, int nb,
                       int* __restrict__ M,
                       const float2* __restrict__ emb, unsigned* __restrict__ q,
                       int n, int cvtb) {
    int histBlocks = gridDim.x - cvtb;
    if ((int)blockIdx.x >= histBlocks) {
        int stride = cvtb * PBLK;
        size_t planeWords = (size_t)(n >> 3);          // N*8 words per plane
        for (int i = ((int)blockIdx.x - histBlocks) * PBLK + threadIdx.x; i < n; i += stride) {
            float2 f = emb[i];
            unsigned lo = __float_as_uint(f.x), hi = __float_as_uint(f.y);
            lo = (lo + 0x7FFFu + ((lo >> 16) & 1u)) & 0xFFFF0000u;   // RNE to bf16
            hi = (hi + 0x7FFFu + ((hi >> 16) & 1u)) & 0xFFFF0000u;
            // i = node*64 + pair; plane = (pair>>3), word-in-plane = node*8 + (pair&7)
            size_t plane = (size_t)((i >> 3) & 7);
            size_t w     = (size_t)(((i >> 6) << 3) | (i & 7));
            q[plane * planeWords + w] = hi | (lo >> 16);
        }
        return;
    }
    extern __shared__ int h[];
    int c = blockIdx.x;
    int slot = PERM(c);
    for (int i = threadIdx.x; i < nb; i += PBLK) h[i] = 0;
    __syncthreads();
    int beg = c * CE, end = min(E, beg + CE);
    for (int e = beg + threadIdx.x; e < end; e += PBLK)
        atomicAdd(&h[rows[e] >> BSHIFT], 1);
    __syncthreads();
    for (int i = threadIdx.x; i < nb; i += PBLK) M[(size_t)i * CHUNKS + slot] = h[i];
}

// ---------- Phase 2: hierarchical exclusive scan (block-local O + block sums bs) ----------
__global__ void k_scan1(const int* __restrict__ M, int flat,
                        int* __restrict__ O, int* __restrict__ bs) {
    __shared__ int s[1024];
    int i = blockIdx.x * 1024 + threadIdx.x;
    int v = (i < flat) ? M[i] : 0;
    s[threadIdx.x] = v;
    __syncthreads();
    for (int off = 1; off < 1024; off <<= 1) {
        int t = (threadIdx.x >= (unsigned)off) ? s[threadIdx.x - off] : 0;
        __syncthreads();
        s[threadIdx.x] += t;
        __syncthreads();
    }
    if (i < flat) O[i] = s[threadIdx.x] - v;
    if (threadIdx.x == 1023) bs[blockIdx.x] = s[1023];
}

__global__ void k_scan2(int* __restrict__ bs, int nblk) {
    __shared__ int s[1024];
    __shared__ int carry;
    if (threadIdx.x == 0) carry = 0;
    __syncthreads();
    for (int base = 0; base < nblk; base += 1024) {
        int i = base + (int)threadIdx.x;
        int v = (i < nblk) ? bs[i] : 0;
        s[threadIdx.x] = v;
        __syncthreads();
        for (int off = 1; off < 1024; off <<= 1) {
            int t = (threadIdx.x >= (unsigned)off) ? s[threadIdx.x - off] : 0;
            __syncthreads();
            s[threadIdx.x] += t;
            __syncthreads();
        }
        int c = carry;
        if (i < nblk) bs[i] = c + s[threadIdx.x] - v;
        __syncthreads();
        if (threadIdx.x == 0) carry = c + s[1023];
        __syncthreads();
    }
}

// ---------- Phase 3: scatter via LDS cursors; final offset = O[f] + bs[f>>10] ----------
__global__ void k_mscatter(const int* __restrict__ rows, const int* __restrict__ cols,
                           const float* __restrict__ vals, int E, int CE, int nb,
                           const int* __restrict__ O, const int* __restrict__ bs,
                           unsigned long long* __restrict__ sorted) {
    extern __shared__ int cur[];
    int c = blockIdx.x;
    int slot = PERM(c);
    for (int b = threadIdx.x; b < nb; b += PBLK) {
        int f = b * CHUNKS + slot;
        cur[b] = O[f] + bs[f >> 10];
    }
    __syncthreads();
    int beg = c * CE, end = min(E, beg + CE);
    for (int e = beg + threadIdx.x; e < end; e += PBLK) {
        int r = rows[e];
        int b = r >> BSHIFT;
        int pos = atomicAdd(&cur[b], 1);
        unsigned packed = ((unsigned)(r & (BROWS - 1)) << COLBITS) | (unsigned)cols[e];
        unsigned long long rec =
            ((unsigned long long)__float_as_uint(vals[e]) << 32) | (unsigned long long)packed;
        if (pos >= 0 && pos < E)                     // normal store: L2 aggregates lines
            sorted[pos] = rec;
    }
}

// ---------- Phase 4 (NEW): dim-sliced LDS-atomic accumulation, XCD-local gathers ----------
// Block (bucket b, plane r = blockIdx&7) computes out[b*32 .. b*32+32)[16r .. 16r+16).
// No per-tile counting sort: the 32x16 output tile lives in LDS; records are streamed
// ONCE and accumulated with ds_add_f32. Lane layout: eblk = tid>>3 (32 edges in flight
// per block), dw = tid&7 (one u32 = 2 bf16 dims).
__global__ __launch_bounds__(256) void k_dimacc(const int2* __restrict__ sorted,
                                                const int* __restrict__ O,
                                                const int* __restrict__ bs,
                                                const unsigned* __restrict__ q,
                                                float* __restrict__ out,
                                                int N, int nb, int E) {
    __shared__ float acc[BROWS * ASTRIDE];           // 32*17*4 = 2176 B
    int r = blockIdx.x & (DSPLIT - 1);
    int b = blockIdx.x >> 3;
    int f0 = b * CHUNKS;                             // PERM(0)==0: bucket's first slot
    int beg = O[f0] + bs[f0 >> 10];
    int end;
    if (b + 1 < nb) { int f1 = (b + 1) * CHUNKS; end = O[f1] + bs[f1 >> 10]; }
    else            end = E;
    beg = max(0, min(beg, E));
    end = max(beg, min(end, E));

    for (int i = threadIdx.x; i < BROWS * ASTRIDE; i += 256) acc[i] = 0.f;
    __syncthreads();

    const unsigned* plane = q + (size_t)r * ((size_t)N * DIMW);
    int eblk = threadIdx.x >> 3;                     // 0..31: edge slot within block
    int dw   = threadIdx.x & 7;                      // 0..7:  u32 word within plane row

    for (int j0 = beg; j0 < end; j0 += 128) {        // 128 edges per block-iteration
        int2  rc[4];
        float vv[4];
#pragma unroll
        for (int k = 0; k < 4; ++k) {
            int idx = j0 + (k << 5) + eblk;
            bool okE = idx < end;
            int safe = okE ? idx : beg;              // beg < end inside this loop
            rc[k] = sorted[safe];
            vv[k] = okE ? __int_as_float(rc[k].y) : 0.f;
        }
        unsigned uu[4];
#pragma unroll
        for (int k = 0; k < 4; ++k)
            uu[k] = plane[(size_t)((unsigned)rc[k].x & COLMASK) * DIMW + dw];
#pragma unroll
        for (int k = 0; k < 4; ++k) {
            int   row = (int)((((unsigned)rc[k].x) >> COLBITS) & (BROWS - 1));
            float vx  = vv[k] * __uint_as_float(uu[k] << 16);
            float vy  = vv[k] * __uint_as_float(uu[k] & 0xFFFF0000u);
            int   a   = row * ASTRIDE + (dw << 1);
            atomicAdd(&acc[a],     vx);
            atomicAdd(&acc[a + 1], vy);
        }
    }
    __syncthreads();

    // flush the 32x16 tile: disjoint slice of out, nontemporal (never re-read)
    size_t rowbase = (size_t)b * BROWS;
#pragma unroll
    for (int i = threadIdx.x; i < BROWS * 16; i += 256) {
        int row = i >> 4, d = i & 15;
        size_t orow = rowbase + row;
        if (orow < (size_t)N)
            __builtin_nontemporal_store(acc[row * ASTRIDE + d],
                                        out + orow * D + r * 16 + d);
    }
}

// ---------- Fallback phase 4 (f32 workspace-tight path): original bucket kernel ----------
__global__ __launch_bounds__(256) void k_bucket2f(const int2* __restrict__ sorted,
                                                  const int* __restrict__ O,
                                                  const int* __restrict__ bs,
                                                  const float2* __restrict__ e2,
                                                  float* __restrict__ out,
                                                  int N, int nb, int E) {
    __shared__ int rowcnt[BROWS], rowoff[BROWS], rowcur[BROWS];
    __shared__ int2 rec2[CAP];
    int b  = blockIdx.x;
    int f0 = b * CHUNKS;
    int beg = O[f0] + bs[f0 >> 10];
    int end;
    if (b + 1 < nb) { int f1 = (b + 1) * CHUNKS; end = O[f1] + bs[f1 >> 10]; }
    else            end = E;
    beg = max(0, min(beg, E));
    end = max(beg, min(end, E));
    int wid = threadIdx.x >> 6, lane = threadIdx.x & 63;

    float2 acc[8];
#pragma unroll
    for (int q = 0; q < 8; ++q) acc[q] = make_float2(0.f, 0.f);

    for (int done = beg; done < end; done += CAP) {
        int cnt = min(CAP, end - done);
        if (threadIdx.x < BROWS) rowcnt[threadIdx.x] = 0;
        __syncthreads();
        for (int k = threadIdx.x; k < cnt; k += 256)
            atomicAdd(&rowcnt[(((unsigned)sorted[done + k].x) >> COLBITS) & (BROWS - 1)], 1);
        __syncthreads();
        if (threadIdx.x < BROWS) {
            int v = rowcnt[threadIdx.x];
            int incl = v;
#pragma unroll
            for (int off = 1; off < BROWS; off <<= 1) {
                int u = __shfl_up(incl, off);
                if ((int)threadIdx.x >= off) incl += u;
            }
            rowoff[threadIdx.x] = incl - v;
            rowcur[threadIdx.x] = incl - v;
        }
        __syncthreads();
        for (int k = threadIdx.x; k < cnt; k += 256) {
            int2 rr = sorted[done + k];
            int row = (((unsigned)rr.x) >> COLBITS) & (BROWS - 1);
            int pos = atomicAdd(&rowcur[row], 1);
            if (pos >= 0 && pos < CAP) rec2[pos] = rr;
        }
        __syncthreads();

#pragma unroll
        for (int q = 0; q < 8; ++q) {
            int row = wid * 8 + q;
            int off = rowoff[row], cr = rowcnt[row];
            int j = 0;
            for (; j + 4 <= cr; j += 4) {
                int2 r0 = rec2[off + j];     int2 r1 = rec2[off + j + 1];
                int2 r2 = rec2[off + j + 2]; int2 r3 = rec2[off + j + 3];
                float v0 = __int_as_float(r0.y), v1 = __int_as_float(r1.y);
                float v2 = __int_as_float(r2.y), v3 = __int_as_float(r3.y);
                float2 e0 = e2[(size_t)(r0.x & COLMASK) * 64 + lane];
                float2 e1 = e2[(size_t)(r1.x & COLMASK) * 64 + lane];
                float2 e2v = e2[(size_t)(r2.x & COLMASK) * 64 + lane];
                float2 e3 = e2[(size_t)(r3.x & COLMASK) * 64 + lane];
                acc[q].x += v0 * e0.x;  acc[q].y += v0 * e0.y;
                acc[q].x += v1 * e1.x;  acc[q].y += v1 * e1.y;
                acc[q].x += v2 * e2v.x; acc[q].y += v2 * e2v.y;
                acc[q].x += v3 * e3.x;  acc[q].y += v3 * e3.y;
            }
            for (; j < cr; ++j) {
                int2 r0 = rec2[off + j];
                float v0 = __int_as_float(r0.y);
                float2 e0 = e2[(size_t)(r0.x & COLMASK) * 64 + lane];
                acc[q].x += v0 * e0.x;
                acc[q].y += v0 * e0.y;
            }
        }
        __syncthreads();
    }

    size_t rowbase = (size_t)b * BROWS;
    unsigned long long* out64 = (unsigned long long*)out;
#pragma unroll
    for (int q = 0; q < 8; ++q) {
        size_t row = rowbase + wid * 8 + q;
        if (row < (size_t)N) {
            unsigned long long p =
                ((unsigned long long)__float_as_uint(acc[q].y) << 32) |
                (unsigned long long)__float_as_uint(acc[q].x);
            __builtin_nontemporal_store(p, out64 + row * 64 + lane);
        }
    }
}

// ---------- Fallback: direct atomic scatter-add ----------
__global__ void k_atomic(const int* __restrict__ rows, const int* __restrict__ cols,
                         const float* __restrict__ vals, const float2* __restrict__ emb,
                         float* __restrict__ out, int E) {
    long long g = (long long)blockIdx.x * blockDim.x + threadIdx.x;
    int e    = (int)(g >> 6);
    int lane = (int)(g & 63);
    if (e >= E) return;
    int r = rows[e], c = cols[e];
    float v = vals[e];
    float2 em = emb[(size_t)c * (D / 2) + lane];
    atomicAdd(&out[(size_t)r * D + lane * 2    ], v * em.x);
    atomicAdd(&out[(size_t)r * D + lane * 2 + 1], v * em.y);
}

extern "C" void kernel_launch(void* const* d_in, const int* in_sizes, int n_in,
                              void* d_out, int out_size, void* d_ws, size_t ws_size,
                              hipStream_t stream) {
    const int*   adj  = (const int*)d_in[0];
    const float* vals = (const float*)d_in[1];
    const float* emb  = (const float*)d_in[2];
    int E = in_sizes[1];
    int N = in_sizes[2] / D;
    const int* rows = adj;
    const int* cols = adj + E;
    float* out = (float*)d_out;

    int nb   = (N + BROWS - 1) / BROWS;
    int CE   = (E + CHUNKS - 1) / CHUNKS;
    int flat = nb * CHUNKS;
    int nblk = (flat + 1023) / 1024;

    size_t off_sorted = 0;
    size_t sz_sorted  = (size_t)E * 8;
    size_t off_M      = (off_sorted + sz_sorted + 255) & ~(size_t)255;
    size_t sz_M       = (size_t)flat * 4;
    size_t off_O      = (off_M + sz_M + 255) & ~(size_t)255;
    size_t sz_O       = (size_t)flat * 4;
    size_t off_bs     = (off_O + sz_O + 255) & ~(size_t)255;
    size_t sz_bs      = (size_t)nblk * 4;
    size_t off_q      = (off_bs + sz_bs + 255) & ~(size_t)255;
    size_t sz_q       = (size_t)N * 64 * 4;
    size_t need_bf16  = off_q + sz_q;
    size_t need_f32   = off_q;

    bool ok = (N <= (1 << COLBITS)) && ((size_t)nb * 4 <= 60000) && (nblk <= 1024);

    if (ok && ws_size >= need_f32) {
        char* ws = (char*)d_ws;
        unsigned long long* sorted = (unsigned long long*)(ws + off_sorted);
        int* M  = (int*)(ws + off_M);
        int* O  = (int*)(ws + off_O);
        int* bs = (int*)(ws + off_bs);
        bool bf16 = (ws_size >= need_bf16);
        unsigned* q = (unsigned*)(ws + off_q);

        int cvtb = bf16 ? CVTB : 0;
        k_prep    <<<CHUNKS + cvtb, PBLK, (size_t)nb * 4, stream>>>(
                      rows, E, CE, nb, M, (const float2*)emb, q, N * 64, cvtb);
        k_scan1   <<<nblk, 1024, 0, stream>>>(M, flat, O, bs);
        k_scan2   <<<1, 1024, 0, stream>>>(bs, nblk);
        k_mscatter<<<CHUNKS, PBLK, (size_t)nb * 4, stream>>>(
                      rows, cols, vals, E, CE, nb, O, bs, sorted);
        if (bf16) {
            // grid = nb * 8: blockIdx&7 = dim-plane = XCD (round-robin dispatch)
            k_dimacc<<<nb * DSPLIT, 256, 0, stream>>>((const int2*)sorted, O, bs,
                                                      q, out, N, nb, E);
        } else {
            k_bucket2f<<<nb, 256, 0, stream>>>((const int2*)sorted, O, bs,
                                               (const float2*)emb, out, N, nb, E);
        }
    } else {
        hipMemsetAsync(out, 0, (size_t)out_size * sizeof(float), stream);
        long long tot = (long long)E * 64;
        int blocks = (int)((tot + 255) / 256);
        k_atomic<<<blocks, 256, 0, stream>>>(rows, cols, vals, (const float2*)emb, out, E);
    }
}

// Round 3
// 894.941 us; speedup vs baseline: 2.7131x; 2.7131x over previous
//
#include <hip/hip_runtime.h>

#define D 128
#define BROWS 32
#define COLBITS 17
#define CVTB 1792
#define HISTB 256
#define PBLK 1024
#define DSPLIT 8      // embedding-dim split: 8 planes of 16 dims (3.3 MB each -> L2-resident per XCD)
#define DIMW 8        // u32 words (2 bf16 dims each) per plane per node

// ---------- Phase 1 (fused): per-ROW global histogram + emb fp32->bf16 plane convert ----------
// bf16 table is PLANE-MAJOR: q[plane][node][8 words], plane = dim/16. Each 3.3 MB plane is
// gathered only by phase-4 blocks with blockIdx%8 == plane -> stays in one XCD's L2.
__global__ void k_prep(const int* __restrict__ rows, int E,
                       int* __restrict__ cnt,
                       const float2* __restrict__ emb, unsigned* __restrict__ q,
                       int n, int cvtb) {
    int histBlocks = gridDim.x - cvtb;
    if ((int)blockIdx.x >= histBlocks) {
        int stride = cvtb * PBLK;
        size_t planeWords = (size_t)(n >> 3);          // N*8 words per plane
        for (int i = ((int)blockIdx.x - histBlocks) * PBLK + threadIdx.x; i < n; i += stride) {
            float2 f = emb[i];
            unsigned lo = __float_as_uint(f.x), hi = __float_as_uint(f.y);
            lo = (lo + 0x7FFFu + ((lo >> 16) & 1u)) & 0xFFFF0000u;   // RNE to bf16
            hi = (hi + 0x7FFFu + ((hi >> 16) & 1u)) & 0xFFFF0000u;
            // i = node*64 + pair; plane = (pair>>3), word-in-plane = node*8 + (pair&7)
            size_t plane = (size_t)((i >> 3) & 7);
            size_t w     = (size_t)(((i >> 6) << 3) | (i & 7));
            q[plane * planeWords + w] = hi | (lo >> 16);
        }
        return;
    }
    int stride = histBlocks * PBLK;
    for (int e = (int)blockIdx.x * PBLK + threadIdx.x; e < E; e += stride)
        atomicAdd(&cnt[rows[e]], 1);                   // int atomic: native, device-scope
}

// ---------- Phase 2: hierarchical exclusive scan over N row counts ----------
__global__ void k_scan1(const int* __restrict__ M, int flat,
                        int* __restrict__ O, int* __restrict__ bs) {
    __shared__ int s[1024];
    int i = blockIdx.x * 1024 + threadIdx.x;
    int v = (i < flat) ? M[i] : 0;
    s[threadIdx.x] = v;
    __syncthreads();
    for (int off = 1; off < 1024; off <<= 1) {
        int t = (threadIdx.x >= (unsigned)off) ? s[threadIdx.x - off] : 0;
        __syncthreads();
        s[threadIdx.x] += t;
        __syncthreads();
    }
    if (i < flat) O[i] = s[threadIdx.x] - v;
    if (threadIdx.x == 1023) bs[blockIdx.x] = s[1023];
}

__global__ void k_scan2(int* __restrict__ bs, int nblk) {
    __shared__ int s[1024];
    __shared__ int carry;
    if (threadIdx.x == 0) carry = 0;
    __syncthreads();
    for (int base = 0; base < nblk; base += 1024) {
        int i = base + (int)threadIdx.x;
        int v = (i < nblk) ? bs[i] : 0;
        s[threadIdx.x] = v;
        __syncthreads();
        for (int off = 1; off < 1024; off <<= 1) {
            int t = (threadIdx.x >= (unsigned)off) ? s[threadIdx.x - off] : 0;
            __syncthreads();
            s[threadIdx.x] += t;
            __syncthreads();
        }
        int c = carry;
        if (i < nblk) bs[i] = c + s[threadIdx.x] - v;
        __syncthreads();
        if (threadIdx.x == 0) carry = c + s[1023];
        __syncthreads();
    }
}

__global__ void k_mkcur(const int* __restrict__ O, const int* __restrict__ bs,
                        int* __restrict__ cur, int N) {
    int i = blockIdx.x * 1024 + threadIdx.x;
    if (i < N) cur[i] = O[i] + bs[i >> 10];
}

// ---------- Phase 3: row-sorted scatter via global atomic cursors ----------
// After this kernel, cur[r] == end of row r's run; start(r) == cur[r-1] (or 0).
__global__ void k_rscatter(const int* __restrict__ rows, const int* __restrict__ cols,
                           const float* __restrict__ vals, int E,
                           int* __restrict__ cur,
                           unsigned long long* __restrict__ sorted) {
    int e = blockIdx.x * 1024 + threadIdx.x;
    if (e >= E) return;
    int r = rows[e];
    int pos = atomicAdd(&cur[r], 1);
    unsigned long long rec =
        ((unsigned long long)__float_as_uint(vals[e]) << 32) | (unsigned)cols[e];
    if (pos >= 0 && pos < E) sorted[pos] = rec;
}

// ---------- Phase 4: dim-sliced row-run streaming, XCD-local gathers, zero LDS ----------
// Block (bucket b, plane r=blockIdx&7) computes out[b*32..+32)[16r..16r+16).
// Lane layout: e8 = lane>>3 (8 edges in flight), dw = lane&7 (one u32 = 2 bf16 dims).
// Records are row-sorted so each row is a contiguous run: no binning, VGPR accumulation.
__global__ __launch_bounds__(256) void k_dimstream(const unsigned long long* __restrict__ sorted,
                                                   const int* __restrict__ cur,
                                                   const unsigned* __restrict__ q,
                                                   float* __restrict__ out,
                                                   int N, int E) {
    int r = blockIdx.x & (DSPLIT - 1);
    int b = blockIdx.x >> 3;
    const unsigned* plane = q + (size_t)r * ((size_t)N * DIMW);
    int wid = threadIdx.x >> 6, lane = threadIdx.x & 63;
    int e8 = lane >> 3, dw = lane & 7;
    int rowbase = b * BROWS + wid * 8;

    float ax[8], ay[8];
#pragma unroll
    for (int k = 0; k < 8; ++k) { ax[k] = 0.f; ay[k] = 0.f; }

#pragma unroll
    for (int qq = 0; qq < 8; ++qq) {
        int row = rowbase + qq;
        if (row >= N) break;
        int jb = (row == 0) ? 0 : cur[row - 1];
        int je = cur[row];
        jb = max(0, min(jb, E));
        je = max(jb, min(je, E));
        if (jb == je) continue;
        float sx = 0.f, sy = 0.f;
        int j = jb;
        for (; j + 32 <= je; j += 32) {                // 4 groups of 8 edges in flight
            unsigned long long r0 = __builtin_nontemporal_load(sorted + j      + e8);
            unsigned long long r1 = __builtin_nontemporal_load(sorted + j +  8 + e8);
            unsigned long long r2 = __builtin_nontemporal_load(sorted + j + 16 + e8);
            unsigned long long r3 = __builtin_nontemporal_load(sorted + j + 24 + e8);
            unsigned u0 = plane[(size_t)(unsigned)(r0 & 0xFFFFFFFFu) * DIMW + dw];
            unsigned u1 = plane[(size_t)(unsigned)(r1 & 0xFFFFFFFFu) * DIMW + dw];
            unsigned u2 = plane[(size_t)(unsigned)(r2 & 0xFFFFFFFFu) * DIMW + dw];
            unsigned u3 = plane[(size_t)(unsigned)(r3 & 0xFFFFFFFFu) * DIMW + dw];
            float v0 = __uint_as_float((unsigned)(r0 >> 32));
            float v1 = __uint_as_float((unsigned)(r1 >> 32));
            float v2 = __uint_as_float((unsigned)(r2 >> 32));
            float v3 = __uint_as_float((unsigned)(r3 >> 32));
            sx += v0 * __uint_as_float(u0 << 16);  sy += v0 * __uint_as_float(u0 & 0xFFFF0000u);
            sx += v1 * __uint_as_float(u1 << 16);  sy += v1 * __uint_as_float(u1 & 0xFFFF0000u);
            sx += v2 * __uint_as_float(u2 << 16);  sy += v2 * __uint_as_float(u2 & 0xFFFF0000u);
            sx += v3 * __uint_as_float(u3 << 16);  sy += v3 * __uint_as_float(u3 & 0xFFFF0000u);
        }
        for (; j < je; j += 8) {
            int idx = j + e8;
            bool m = idx < je;
            unsigned long long r0 = __builtin_nontemporal_load(sorted + (m ? idx : jb));
            unsigned u0 = plane[(size_t)(unsigned)(r0 & 0xFFFFFFFFu) * DIMW + dw];
            float v0 = m ? __uint_as_float((unsigned)(r0 >> 32)) : 0.f;
            sx += v0 * __uint_as_float(u0 << 16);
            sy += v0 * __uint_as_float(u0 & 0xFFFF0000u);
        }
        ax[qq] = sx; ay[qq] = sy;
    }

    // reduce over the 8 edge-slots (lane bits 3..5), nt-store 8 B per row
    unsigned long long* out64 = (unsigned long long*)out;
#pragma unroll
    for (int qq = 0; qq < 8; ++qq) {
        float sx = ax[qq], sy = ay[qq];
        sx += __shfl_xor(sx, 8);  sy += __shfl_xor(sy, 8);
        sx += __shfl_xor(sx, 16); sy += __shfl_xor(sy, 16);
        sx += __shfl_xor(sx, 32); sy += __shfl_xor(sy, 32);
        int row = rowbase + qq;
        if (row < N && e8 == 0) {
            unsigned long long p =
                ((unsigned long long)__float_as_uint(sy) << 32) |
                (unsigned long long)__float_as_uint(sx);
            __builtin_nontemporal_store(p, out64 + (size_t)row * 64 + r * DIMW + dw);
        }
    }
}

// ---------- Phase 4 fallback (f32, full-D): row-run streaming from emb ----------
__global__ __launch_bounds__(256) void k_fullstream(const unsigned long long* __restrict__ sorted,
                                                    const int* __restrict__ cur,
                                                    const float2* __restrict__ e2,
                                                    float* __restrict__ out,
                                                    int N, int E) {
    int b = blockIdx.x;
    int wid = threadIdx.x >> 6, lane = threadIdx.x & 63;
    unsigned long long* out64 = (unsigned long long*)out;
#pragma unroll
    for (int qq = 0; qq < 8; ++qq) {
        int row = b * BROWS + wid * 8 + qq;
        if (row >= N) break;
        int jb = (row == 0) ? 0 : cur[row - 1];
        int je = cur[row];
        jb = max(0, min(jb, E));
        je = max(jb, min(je, E));
        float sx = 0.f, sy = 0.f;
        int j = jb;
        for (; j + 4 <= je; j += 4) {
            unsigned long long r0 = sorted[j],     r1 = sorted[j + 1];
            unsigned long long r2 = sorted[j + 2], r3 = sorted[j + 3];
            float2 g0 = e2[(size_t)(unsigned)(r0 & 0xFFFFFFFFu) * 64 + lane];
            float2 g1 = e2[(size_t)(unsigned)(r1 & 0xFFFFFFFFu) * 64 + lane];
            float2 g2 = e2[(size_t)(unsigned)(r2 & 0xFFFFFFFFu) * 64 + lane];
            float2 g3 = e2[(size_t)(unsigned)(r3 & 0xFFFFFFFFu) * 64 + lane];
            float v0 = __uint_as_float((unsigned)(r0 >> 32));
            float v1 = __uint_as_float((unsigned)(r1 >> 32));
            float v2 = __uint_as_float((unsigned)(r2 >> 32));
            float v3 = __uint_as_float((unsigned)(r3 >> 32));
            sx += v0 * g0.x; sy += v0 * g0.y;
            sx += v1 * g1.x; sy += v1 * g1.y;
            sx += v2 * g2.x; sy += v2 * g2.y;
            sx += v3 * g3.x; sy += v3 * g3.y;
        }
        for (; j < je; ++j) {
            unsigned long long r0 = sorted[j];
            float2 g0 = e2[(size_t)(unsigned)(r0 & 0xFFFFFFFFu) * 64 + lane];
            float v0 = __uint_as_float((unsigned)(r0 >> 32));
            sx += v0 * g0.x; sy += v0 * g0.y;
        }
        unsigned long long p =
            ((unsigned long long)__float_as_uint(sy) << 32) |
            (unsigned long long)__float_as_uint(sx);
        __builtin_nontemporal_store(p, out64 + (size_t)row * 64 + lane);
    }
}

// ---------- Fallback: direct atomic scatter-add ----------
__global__ void k_atomic(const int* __restrict__ rows, const int* __restrict__ cols,
                         const float* __restrict__ vals, const float2* __restrict__ emb,
                         float* __restrict__ out, int E) {
    long long g = (long long)blockIdx.x * blockDim.x + threadIdx.x;
    int e    = (int)(g >> 6);
    int lane = (int)(g & 63);
    if (e >= E) return;
    int r = rows[e], c = cols[e];
    float v = vals[e];
    float2 em = emb[(size_t)c * (D / 2) + lane];
    atomicAdd(&out[(size_t)r * D + lane * 2    ], v * em.x);
    atomicAdd(&out[(size_t)r * D + lane * 2 + 1], v * em.y);
}

extern "C" void kernel_launch(void* const* d_in, const int* in_sizes, int n_in,
                              void* d_out, int out_size, void* d_ws, size_t ws_size,
                              hipStream_t stream) {
    const int*   adj  = (const int*)d_in[0];
    const float* vals = (const float*)d_in[1];
    const float* emb  = (const float*)d_in[2];
    int E = in_sizes[1];
    int N = in_sizes[2] / D;
    const int* rows = adj;
    const int* cols = adj + E;
    float* out = (float*)d_out;

    int nb   = (N + BROWS - 1) / BROWS;
    int nblk = (N + 1023) / 1024;

    size_t off_sorted = 0;
    size_t sz_sorted  = (size_t)E * 8;
    size_t off_cnt    = (off_sorted + sz_sorted + 255) & ~(size_t)255;
    size_t sz_cnt     = (size_t)N * 4;
    size_t off_O      = (off_cnt + sz_cnt + 255) & ~(size_t)255;
    size_t sz_O       = (size_t)N * 4;
    size_t off_bs     = (off_O + sz_O + 255) & ~(size_t)255;
    size_t sz_bs      = (size_t)(nblk > 0 ? nblk : 1) * 4;
    size_t off_cur    = (off_bs + sz_bs + 255) & ~(size_t)255;
    size_t sz_cur     = (size_t)N * 4;
    size_t off_q      = (off_cur + sz_cur + 255) & ~(size_t)255;
    size_t sz_q       = (size_t)N * 256;               // bf16 planes: N*64 u32
    size_t need_bf16  = off_q + sz_q;
    size_t need_f32   = off_q;

    bool ok = (N > 0) && (E > 0) && (N <= (1 << COLBITS)) && (nblk <= 1024);

    if (ok && ws_size >= need_f32) {
        char* ws = (char*)d_ws;
        unsigned long long* sorted = (unsigned long long*)(ws + off_sorted);
        int* cnt = (int*)(ws + off_cnt);
        int* O   = (int*)(ws + off_O);
        int* bs  = (int*)(ws + off_bs);
        int* cur = (int*)(ws + off_cur);
        bool bf16 = (ws_size >= need_bf16);
        unsigned* q = (unsigned*)(ws + off_q);

        hipMemsetAsync(cnt, 0, sz_cnt, stream);
        int cvtb = bf16 ? CVTB : 0;
        k_prep    <<<HISTB + cvtb, PBLK, 0, stream>>>(rows, E, cnt,
                      (const float2*)emb, q, N * 64, cvtb);
        k_scan1   <<<nblk, 1024, 0, stream>>>(cnt, N, O, bs);
        k_scan2   <<<1, 1024, 0, stream>>>(bs, nblk);
        k_mkcur   <<<nblk, 1024, 0, stream>>>(O, bs, cur, N);
        k_rscatter<<<(E + 1023) / 1024, 1024, 0, stream>>>(rows, cols, vals, E, cur, sorted);
        if (bf16) {
            // grid = nb*8: blockIdx&7 = dim-plane = XCD (round-robin dispatch)
            k_dimstream<<<nb * DSPLIT, 256, 0, stream>>>(sorted, cur, q, out, N, E);
        } else {
            k_fullstream<<<nb, 256, 0, stream>>>(sorted, cur, (const float2*)emb, out, N, E);
        }
    } else {
        hipMemsetAsync(out, 0, (size_t)out_size * sizeof(float), stream);
        long long tot = (long long)E * 64;
        int blocks = (int)((tot + 255) / 256);
        k_atomic<<<blocks, 256, 0, stream>>>(rows, cols, vals, (const float2*)emb, out, E);
    }
}

// Round 5
// 394.014 us; speedup vs baseline: 6.1623x; 2.2713x over previous
//
#include <hip/hip_runtime.h>

#define D 128
#define BROWS 32
#define BSHIFT 5
#define COLBITS 17
#define COLMASK 0x1FFFF
#define CHUNKS 256
#define CAP 1280
#define CVTB 1792
#define PBLK 1024
#define DSPLIT 8      // embedding-dim split: 8 planes of 16 dims (3.3 MB each -> L2-resident per XCD)
#define DIMW 8        // u32 words (2 bf16 dims each) per plane per node
#define RSCAP 4096    // max bucket run sorted in-place via LDS (mean 1024, sigma 32)
#define TCAP 1536     // phase-4 LDS staging chunk (12 KB)
// XCD-grouping permutation of chunk->matrix-slot (valid for CHUNKS==256)
#define PERM(c) ((((c) & 7) << 5) | ((c) >> 3))

// ---------- Phase 1 (fused): per-chunk bucket histogram + emb fp32->bf16 plane convert ----------
__global__ void k_prep(const int* __restrict__ rows, int E, int CE, int nb,
                       int* __restrict__ M,
                       const float2* __restrict__ emb, unsigned* __restrict__ q,
                       int n, int cvtb) {
    int histBlocks = gridDim.x - cvtb;
    if ((int)blockIdx.x >= histBlocks) {
        int stride = cvtb * PBLK;
        size_t planeWords = (size_t)(n >> 3);          // N*8 words per plane
        for (int i = ((int)blockIdx.x - histBlocks) * PBLK + threadIdx.x; i < n; i += stride) {
            float2 f = emb[i];
            unsigned lo = __float_as_uint(f.x), hi = __float_as_uint(f.y);
            lo = (lo + 0x7FFFu + ((lo >> 16) & 1u)) & 0xFFFF0000u;   // RNE to bf16
            hi = (hi + 0x7FFFu + ((hi >> 16) & 1u)) & 0xFFFF0000u;
            size_t plane = (size_t)((i >> 3) & 7);
            size_t w     = (size_t)(((i >> 6) << 3) | (i & 7));
            q[plane * planeWords + w] = hi | (lo >> 16);
        }
        return;
    }
    extern __shared__ int h[];
    int c = blockIdx.x;
    int slot = PERM(c);
    for (int i = threadIdx.x; i < nb; i += PBLK) h[i] = 0;
    __syncthreads();
    int beg = c * CE, end = min(E, beg + CE);
    for (int e = beg + threadIdx.x; e < end; e += PBLK)
        atomicAdd(&h[rows[e] >> BSHIFT], 1);            // int LDS atomic: native ds_add
    __syncthreads();
    for (int i = threadIdx.x; i < nb; i += PBLK) M[(size_t)i * CHUNKS + slot] = h[i];
}

// ---------- Phase 2: hierarchical exclusive scan ----------
__global__ void k_scan1(const int* __restrict__ M, int flat,
                        int* __restrict__ O, int* __restrict__ bs) {
    __shared__ int s[1024];
    int i = blockIdx.x * 1024 + threadIdx.x;
    int v = (i < flat) ? M[i] : 0;
    s[threadIdx.x] = v;
    __syncthreads();
    for (int off = 1; off < 1024; off <<= 1) {
        int t = (threadIdx.x >= (unsigned)off) ? s[threadIdx.x - off] : 0;
        __syncthreads();
        s[threadIdx.x] += t;
        __syncthreads();
    }
    if (i < flat) O[i] = s[threadIdx.x] - v;
    if (threadIdx.x == 1023) bs[blockIdx.x] = s[1023];
}

__global__ void k_scan2(int* __restrict__ bs, int nblk) {
    __shared__ int s[1024];
    __shared__ int carry;
    if (threadIdx.x == 0) carry = 0;
    __syncthreads();
    for (int base = 0; base < nblk; base += 1024) {
        int i = base + (int)threadIdx.x;
        int v = (i < nblk) ? bs[i] : 0;
        s[threadIdx.x] = v;
        __syncthreads();
        for (int off = 1; off < 1024; off <<= 1) {
            int t = (threadIdx.x >= (unsigned)off) ? s[threadIdx.x - off] : 0;
            __syncthreads();
            s[threadIdx.x] += t;
            __syncthreads();
        }
        int c = carry;
        if (i < nblk) bs[i] = c + s[threadIdx.x] - v;
        __syncthreads();
        if (threadIdx.x == 0) carry = c + s[1023];
        __syncthreads();
    }
}

// ---------- Phase 3: bucket-sorted scatter via LDS cursors (proven round-1) ----------
__global__ void k_mscatter(const int* __restrict__ rows, const int* __restrict__ cols,
                           const float* __restrict__ vals, int E, int CE, int nb,
                           const int* __restrict__ O, const int* __restrict__ bs,
                           unsigned long long* __restrict__ sorted) {
    extern __shared__ int cur[];
    int c = blockIdx.x;
    int slot = PERM(c);
    for (int b = threadIdx.x; b < nb; b += PBLK) {
        int f = b * CHUNKS + slot;
        cur[b] = O[f] + bs[f >> 10];
    }
    __syncthreads();
    int beg = c * CE, end = min(E, beg + CE);
    for (int e = beg + threadIdx.x; e < end; e += PBLK) {
        int r = rows[e];
        int b = r >> BSHIFT;
        int pos = atomicAdd(&cur[b], 1);
        unsigned packed = ((unsigned)(r & (BROWS - 1)) << COLBITS) | (unsigned)cols[e];
        unsigned long long rec =
            ((unsigned long long)__float_as_uint(vals[e]) << 32) | (unsigned long long)packed;
        if (pos >= 0 && pos < E)
            sorted[pos] = rec;
    }
}

// ---------- Phase 3.5: per-bucket in-place row sort + global CSR rowptr ----------
// One block per bucket. Run (mean 1024 recs) staged in LDS, 32-bin counting sort,
// written back in row-sorted order. rowptr[row] = absolute run start (CSR).
// Oversized runs (>RSCAP): left bucket-sorted; rowptr = -(beg)-2 sentinel.
__global__ __launch_bounds__(256) void k_rowsort(unsigned long long* __restrict__ sorted,
                                                 const int* __restrict__ O,
                                                 const int* __restrict__ bs,
                                                 int* __restrict__ rowptr,
                                                 int nb, int N, int E) {
    __shared__ unsigned long long recs[RSCAP];
    __shared__ int cnt[BROWS], cur[BROWS];
    int b = blockIdx.x;
    int f0 = b * CHUNKS;
    int beg = O[f0] + bs[f0 >> 10];
    int end;
    if (b + 1 < nb) { int f1 = (b + 1) * CHUNKS; end = O[f1] + bs[f1 >> 10]; }
    else            end = E;
    beg = max(0, min(beg, E));
    end = max(beg, min(end, E));
    int run = end - beg;
    if (b == 0 && threadIdx.x == 0) rowptr[N] = E;
    if (run > RSCAP) {
        if (threadIdx.x < BROWS) {
            int row = b * BROWS + (int)threadIdx.x;
            if (row < N) rowptr[row] = -beg - 2;       // sentinel, decodes bucket start
        }
        return;
    }
    if (threadIdx.x < BROWS) cnt[threadIdx.x] = 0;
    for (int k = threadIdx.x; k < run; k += 256) recs[k] = sorted[beg + k];
    __syncthreads();
    for (int k = threadIdx.x; k < run; k += 256)
        atomicAdd(&cnt[((unsigned)recs[k] >> COLBITS) & (BROWS - 1)], 1);
    __syncthreads();
    if (threadIdx.x < BROWS) {
        int v = cnt[threadIdx.x];
        int incl = v;
#pragma unroll
        for (int off = 1; off < BROWS; off <<= 1) {
            int u = __shfl_up(incl, off);
            if ((int)threadIdx.x >= off) incl += u;
        }
        int excl = incl - v;
        cur[threadIdx.x] = excl;
        int row = b * BROWS + (int)threadIdx.x;
        if (row < N) rowptr[row] = beg + excl;
    }
    __syncthreads();
    for (int k = threadIdx.x; k < run; k += 256) {
        unsigned long long rc = recs[k];
        int row = ((unsigned)rc >> COLBITS) & (BROWS - 1);
        int pos = atomicAdd(&cur[row], 1);
        if (pos >= 0 && pos < run) sorted[beg + pos] = rc;
    }
}

// ---------- Phase 4: dim-sliced, LDS-staged row-run streaming (no binning) ----------
// Block (bucket b, plane r=blockIdx&7) computes out[b*32..+32)[16r..16r+16).
// Bucket run staged in LDS via coalesced 512 B/wave loads; each wave walks its 8 rows
// as contiguous LDS runs with 4-deep (8-edge x 8-word) gather ILP into the XCD-local plane.
__global__ __launch_bounds__(256) void k_dimtile(const unsigned long long* __restrict__ sorted,
                                                 const int* __restrict__ rowptr,
                                                 const unsigned* __restrict__ q,
                                                 float* __restrict__ out,
                                                 int N, int E) {
    __shared__ unsigned long long recs[TCAP];
    __shared__ int rp[BROWS + 1];
    int r = blockIdx.x & (DSPLIT - 1);
    int b = blockIdx.x >> 3;
    if (threadIdx.x <= BROWS) {
        int row = b * BROWS + (int)threadIdx.x;
        rp[threadIdx.x] = (row <= N) ? rowptr[row] : E;
    }
    __syncthreads();
    int rp0 = rp[0];
    bool srt = rp0 >= 0;                               // sorted bucket?
    int beg = srt ? rp0 : (-rp0 - 2);
    int endv = rp[BROWS];
    int end = (endv >= 0) ? endv : (-endv - 2);
    beg = max(0, min(beg, E));
    end = max(beg, min(end, E));

    const unsigned* plane = q + (size_t)r * ((size_t)N * DIMW);
    int wid = threadIdx.x >> 6, lane = threadIdx.x & 63;
    int e8 = lane >> 3, dw = lane & 7;
    int rowbase = wid * 8;

    float ax[8], ay[8];
#pragma unroll
    for (int k = 0; k < 8; ++k) { ax[k] = 0.f; ay[k] = 0.f; }

    for (int cb = beg; cb < end; cb += TCAP) {
        int cntc = min(TCAP, end - cb);
        __syncthreads();                               // protect previous chunk reads
        for (int k = threadIdx.x; k < cntc; k += 256)
            recs[k] = sorted[cb + k];
        __syncthreads();

        if (srt) {
#pragma unroll
            for (int qq = 0; qq < 8; ++qq) {
                int li = rowbase + qq;
                int gs = rp[li];
                int geR = rp[li + 1];
                int ge = (geR >= 0) ? geR : (-geR - 2);
                int jb = max(gs, cb) - cb;
                int je = min(ge, cb + cntc) - cb;
                if (jb >= je) continue;
                float sx = 0.f, sy = 0.f;
                int j = jb;
                for (; j + 32 <= je; j += 32) {        // 4 groups of 8 edges in flight
                    unsigned long long r0 = recs[j      + e8];
                    unsigned long long r1 = recs[j +  8 + e8];
                    unsigned long long r2 = recs[j + 16 + e8];
                    unsigned long long r3 = recs[j + 24 + e8];
                    unsigned u0 = plane[(size_t)((unsigned)r0 & COLMASK) * DIMW + dw];
                    unsigned u1 = plane[(size_t)((unsigned)r1 & COLMASK) * DIMW + dw];
                    unsigned u2 = plane[(size_t)((unsigned)r2 & COLMASK) * DIMW + dw];
                    unsigned u3 = plane[(size_t)((unsigned)r3 & COLMASK) * DIMW + dw];
                    float v0 = __uint_as_float((unsigned)(r0 >> 32));
                    float v1 = __uint_as_float((unsigned)(r1 >> 32));
                    float v2 = __uint_as_float((unsigned)(r2 >> 32));
                    float v3 = __uint_as_float((unsigned)(r3 >> 32));
                    sx += v0 * __uint_as_float(u0 << 16);  sy += v0 * __uint_as_float(u0 & 0xFFFF0000u);
                    sx += v1 * __uint_as_float(u1 << 16);  sy += v1 * __uint_as_float(u1 & 0xFFFF0000u);
                    sx += v2 * __uint_as_float(u2 << 16);  sy += v2 * __uint_as_float(u2 & 0xFFFF0000u);
                    sx += v3 * __uint_as_float(u3 << 16);  sy += v3 * __uint_as_float(u3 & 0xFFFF0000u);
                }
                for (; j < je; j += 8) {
                    int idx = j + e8;
                    bool m = idx < je;
                    unsigned long long r0 = recs[m ? idx : j];
                    unsigned u0 = plane[(size_t)((unsigned)r0 & COLMASK) * DIMW + dw];
                    float v0 = m ? __uint_as_float((unsigned)(r0 >> 32)) : 0.f;
                    sx += v0 * __uint_as_float(u0 << 16);
                    sy += v0 * __uint_as_float(u0 & 0xFFFF0000u);
                }
                ax[qq] += sx; ay[qq] += sy;
            }
        } else {
            // unsorted (oversized) bucket: predicated accumulate, correct for any order
            for (int j = 0; j < cntc; j += 8) {
                int idx = j + e8;
                bool m = idx < cntc;
                unsigned long long r0 = recs[m ? idx : j];
                unsigned lo = (unsigned)r0;
                int rl = (int)((lo >> COLBITS) & (BROWS - 1));
                unsigned u0 = plane[(size_t)(lo & COLMASK) * DIMW + dw];
                float v0 = m ? __uint_as_float((unsigned)(r0 >> 32)) : 0.f;
                float px = v0 * __uint_as_float(u0 << 16);
                float py = v0 * __uint_as_float(u0 & 0xFFFF0000u);
#pragma unroll
                for (int qq = 0; qq < 8; ++qq) {
                    bool sel = rl == rowbase + qq;
                    ax[qq] += sel ? px : 0.f;
                    ay[qq] += sel ? py : 0.f;
                }
            }
        }
    }

    // reduce over the 8 edge-slots (lane bits 3..5), nt-store 8 B per row
    unsigned long long* out64 = (unsigned long long*)out;
#pragma unroll
    for (int qq = 0; qq < 8; ++qq) {
        float sx = ax[qq], sy = ay[qq];
        sx += __shfl_xor(sx, 8);  sy += __shfl_xor(sy, 8);
        sx += __shfl_xor(sx, 16); sy += __shfl_xor(sy, 16);
        sx += __shfl_xor(sx, 32); sy += __shfl_xor(sy, 32);
        int row = b * BROWS + rowbase + qq;
        if (row < N && e8 == 0) {
            unsigned long long p =
                ((unsigned long long)__float_as_uint(sy) << 32) |
                (unsigned long long)__float_as_uint(sx);
            __builtin_nontemporal_store(p, out64 + (size_t)row * 64 + r * DIMW + dw);
        }
    }
}

// ---------- Fallback phase 4 (f32 workspace-tight path): round-1 bucket kernel ----------
__global__ __launch_bounds__(256) void k_bucket2f(const int2* __restrict__ sorted,
                                                  const int* __restrict__ O,
                                                  const int* __restrict__ bs,
                                                  const float2* __restrict__ e2,
                                                  float* __restrict__ out,
                                                  int N, int nb, int E) {
    __shared__ int rowcnt[BROWS], rowoff[BROWS], rowcur[BROWS];
    __shared__ int2 rec2[CAP];
    int b  = blockIdx.x;
    int f0 = b * CHUNKS;
    int beg = O[f0] + bs[f0 >> 10];
    int end;
    if (b + 1 < nb) { int f1 = (b + 1) * CHUNKS; end = O[f1] + bs[f1 >> 10]; }
    else            end = E;
    beg = max(0, min(beg, E));
    end = max(beg, min(end, E));
    int wid = threadIdx.x >> 6, lane = threadIdx.x & 63;

    float2 acc[8];
#pragma unroll
    for (int q = 0; q < 8; ++q) acc[q] = make_float2(0.f, 0.f);

    for (int done = beg; done < end; done += CAP) {
        int cnt = min(CAP, end - done);
        if (threadIdx.x < BROWS) rowcnt[threadIdx.x] = 0;
        __syncthreads();
        for (int k = threadIdx.x; k < cnt; k += 256)
            atomicAdd(&rowcnt[(((unsigned)sorted[done + k].x) >> COLBITS) & (BROWS - 1)], 1);
        __syncthreads();
        if (threadIdx.x < BROWS) {
            int v = rowcnt[threadIdx.x];
            int incl = v;
#pragma unroll
            for (int off = 1; off < BROWS; off <<= 1) {
                int u = __shfl_up(incl, off);
                if ((int)threadIdx.x >= off) incl += u;
            }
            rowoff[threadIdx.x] = incl - v;
            rowcur[threadIdx.x] = incl - v;
        }
        __syncthreads();
        for (int k = threadIdx.x; k < cnt; k += 256) {
            int2 rr = sorted[done + k];
            int row = (((unsigned)rr.x) >> COLBITS) & (BROWS - 1);
            int pos = atomicAdd(&rowcur[row], 1);
            if (pos >= 0 && pos < CAP) rec2[pos] = rr;
        }
        __syncthreads();

#pragma unroll
        for (int q = 0; q < 8; ++q) {
            int row = wid * 8 + q;
            int off = rowoff[row], cr = rowcnt[row];
            int j = 0;
            for (; j + 4 <= cr; j += 4) {
                int2 r0 = rec2[off + j];     int2 r1 = rec2[off + j + 1];
                int2 r2 = rec2[off + j + 2]; int2 r3 = rec2[off + j + 3];
                float v0 = __int_as_float(r0.y), v1 = __int_as_float(r1.y);
                float v2 = __int_as_float(r2.y), v3 = __int_as_float(r3.y);
                float2 g0 = e2[(size_t)(r0.x & COLMASK) * 64 + lane];
                float2 g1 = e2[(size_t)(r1.x & COLMASK) * 64 + lane];
                float2 g2 = e2[(size_t)(r2.x & COLMASK) * 64 + lane];
                float2 g3 = e2[(size_t)(r3.x & COLMASK) * 64 + lane];
                acc[q].x += v0 * g0.x; acc[q].y += v0 * g0.y;
                acc[q].x += v1 * g1.x; acc[q].y += v1 * g1.y;
                acc[q].x += v2 * g2.x; acc[q].y += v2 * g2.y;
                acc[q].x += v3 * g3.x; acc[q].y += v3 * g3.y;
            }
            for (; j < cr; ++j) {
                int2 r0 = rec2[off + j];
                float v0 = __int_as_float(r0.y);
                float2 g0 = e2[(size_t)(r0.x & COLMASK) * 64 + lane];
                acc[q].x += v0 * g0.x;
                acc[q].y += v0 * g0.y;
            }
        }
        __syncthreads();
    }

    size_t rowbase = (size_t)b * BROWS;
    unsigned long long* out64 = (unsigned long long*)out;
#pragma unroll
    for (int q = 0; q < 8; ++q) {
        size_t row = rowbase + wid * 8 + q;
        if (row < (size_t)N) {
            unsigned long long p =
                ((unsigned long long)__float_as_uint(acc[q].y) << 32) |
                (unsigned long long)__float_as_uint(acc[q].x);
            __builtin_nontemporal_store(p, out64 + row * 64 + lane);
        }
    }
}

// ---------- Fallback: direct atomic scatter-add ----------
__global__ void k_atomic(const int* __restrict__ rows, const int* __restrict__ cols,
                         const float* __restrict__ vals, const float2* __restrict__ emb,
                         float* __restrict__ out, int E) {
    long long g = (long long)blockIdx.x * blockDim.x + threadIdx.x;
    int e    = (int)(g >> 6);
    int lane = (int)(g & 63);
    if (e >= E) return;
    int r = rows[e], c = cols[e];
    float v = vals[e];
    float2 em = emb[(size_t)c * (D / 2) + lane];
    atomicAdd(&out[(size_t)r * D + lane * 2    ], v * em.x);
    atomicAdd(&out[(size_t)r * D + lane * 2 + 1], v * em.y);
}

extern "C" void kernel_launch(void* const* d_in, const int* in_sizes, int n_in,
                              void* d_out, int out_size, void* d_ws, size_t ws_size,
                              hipStream_t stream) {
    const int*   adj  = (const int*)d_in[0];
    const float* vals = (const float*)d_in[1];
    const float* emb  = (const float*)d_in[2];
    int E = in_sizes[1];
    int N = in_sizes[2] / D;
    const int* rows = adj;
    const int* cols = adj + E;
    float* out = (float*)d_out;

    int nb   = (N + BROWS - 1) / BROWS;
    int CE   = (E + CHUNKS - 1) / CHUNKS;
    int flat = nb * CHUNKS;
    int nblk = (flat + 1023) / 1024;

    size_t off_sorted = 0;
    size_t sz_sorted  = (size_t)E * 8;
    size_t off_M      = (off_sorted + sz_sorted + 255) & ~(size_t)255;
    size_t sz_M       = (size_t)flat * 4;               // reused as rowptr[N+1] after scan1
    size_t off_O      = (off_M + sz_M + 255) & ~(size_t)255;
    size_t sz_O       = (size_t)flat * 4;
    size_t off_bs     = (off_O + sz_O + 255) & ~(size_t)255;
    size_t sz_bs      = (size_t)nblk * 4;
    size_t off_q      = (off_bs + sz_bs + 255) & ~(size_t)255;
    size_t sz_q       = (size_t)N * 256;                // bf16 planes: N*64 u32
    size_t need_bf16  = off_q + sz_q;
    size_t need_f32   = off_q;

    bool ok = (N > 0) && (E > 0) && (N <= (1 << COLBITS)) &&
              ((size_t)nb * 4 <= 60000) && (nblk <= 1024) &&
              (sz_M >= (size_t)(N + 1) * 4);

    if (ok && ws_size >= need_f32) {
        char* ws = (char*)d_ws;
        unsigned long long* sorted = (unsigned long long*)(ws + off_sorted);
        int* M      = (int*)(ws + off_M);
        int* rowptr = (int*)(ws + off_M);               // alias: M dead after k_scan1
        int* O      = (int*)(ws + off_O);
        int* bs     = (int*)(ws + off_bs);
        bool bf16 = (ws_size >= need_bf16);
        unsigned* q = (unsigned*)(ws + off_q);

        int cvtb = bf16 ? CVTB : 0;
        k_prep    <<<CHUNKS + cvtb, PBLK, (size_t)nb * 4, stream>>>(
                      rows, E, CE, nb, M, (const float2*)emb, q, N * 64, cvtb);
        k_scan1   <<<nblk, 1024, 0, stream>>>(M, flat, O, bs);
        k_scan2   <<<1, 1024, 0, stream>>>(bs, nblk);
        k_mscatter<<<CHUNKS, PBLK, (size_t)nb * 4, stream>>>(
                      rows, cols, vals, E, CE, nb, O, bs, sorted);
        if (bf16) {
            k_rowsort<<<nb, 256, 0, stream>>>(sorted, O, bs, rowptr, nb, N, E);
            // grid = nb*8: blockIdx&7 = dim-plane = XCD (round-robin dispatch)
            k_dimtile<<<nb * DSPLIT, 256, 0, stream>>>(sorted, rowptr, q, out, N, E);
        } else {
            k_bucket2f<<<nb, 256, 0, stream>>>((const int2*)sorted, O, bs,
                                               (const float2*)emb, out, N, nb, E);
        }
    } else {
        hipMemsetAsync(out, 0, (size_t)out_size * sizeof(float), stream);
        long long tot = (long long)E * 64;
        int blocks = (int)((tot + 255) / 256);
        k_atomic<<<blocks, 256, 0, stream>>>(rows, cols, vals, (const float2*)emb, out, E);
    }
}